// Round 2
// baseline (719.953 us; speedup 1.0000x reference)
//
#include <hip/hip_runtime.h>

#define DIM 32
#define NB  6

// One block = one (b, i) row of 256 j-elements. Block recomputes the tiny
// per-batch conditioning constants in its prologue (no workspace needed).
// All tensors are float32 per the reference.
__global__ __launch_bounds__(256) void sep_kernel(
    const float* __restrict__ coords,
    const float* __restrict__ x_params,
    const float* __restrict__ t_params,
    const float* __restrict__ xW1, const float* __restrict__ xb1,
    const float* __restrict__ xW2, const float* __restrict__ xb2,
    const float* __restrict__ tW1, const float* __restrict__ tb1,
    const float* __restrict__ tW2, const float* __restrict__ tb2,
    const float* __restrict__ h0,  const float* __restrict__ gh0,
    const float* __restrict__ f_Wh, const float* __restrict__ f_bh,
    const float* __restrict__ f_Wz, const float* __restrict__ f_bz,
    const float* __restrict__ g_Wh, const float* __restrict__ g_bh,
    const float* __restrict__ g_Wz, const float* __restrict__ g_bz,
    const float* __restrict__ d_W,  const float* __restrict__ d_b,
    float* __restrict__ out)
{
    __shared__ float sA[NB * DIM * DIM];   // f_Wh during f-scan, then g_Wh
    __shared__ float sB[NB * DIM * DIM];   // g_Wz[:, :32, :] (the h-dependent part)
    __shared__ float sfz0[NB * DIM], sfz1[NB * DIM];
    __shared__ float sCf[NB * DIM], sCg[NB * DIM];
    __shared__ float shx[DIM], sht[DIM], sex[DIM], set_[DIM];
    __shared__ float sC0[DIM], sG0[DIM], sdW[DIM];

    const int tid = threadIdx.x;
    const int b   = blockIdx.x >> 8;    // 256 blocks per batch
    const int i   = blockIdx.x & 255;   // t index (first N axis)
    const int j   = tid;                // x index (second N axis)

    // ---- stage weights into LDS (float4 loads) ----
    {
        const float4* src = (const float4*)f_Wh;          // 1536 float4s
        float4* dst = (float4*)sA;
        for (int idx = tid; idx < NB * DIM * DIM / 4; idx += 256) dst[idx] = src[idx];
    }
    {
        // g_Wz[k, 0:32, :] -> sB[k,:,:]   (k*64+r)*32 + d, as float4s
        const float4* src = (const float4*)g_Wz;
        float4* dst = (float4*)sB;
        for (int idx = tid; idx < NB * DIM * DIM / 4; idx += 256) {
            int k = idx >> 8, rem = idx & 255;            // rem = r*8+q
            dst[idx] = src[(k * 64) * 8 + rem];
        }
    }
    if (tid < NB * DIM) {           // 192
        int k = tid >> 5, d = tid & 31;
        sfz0[tid] = f_Wz[(k * 34 + 0) * 32 + d]; // x row
        sfz1[tid] = f_Wz[(k * 34 + 1) * 32 + d]; // t row
    }
    if (tid < 32) { sC0[tid] = h0[tid]; sG0[tid] = gh0[tid]; sdW[tid] = d_W[tid]; }

    // ---- per-batch encoders: ex = sin(xp@W1+b1)@W2+b2 ; et likewise ----
    if (tid < 32) {
        float a = xb1[tid];
        for (int k = 0; k < 16; ++k) a = fmaf(x_params[b * 16 + k], xW1[k * 32 + tid], a);
        shx[tid] = __sinf(a);
    } else if (tid < 64) {
        int d = tid - 32;
        float a = tb1[d];
        for (int k = 0; k < 8; ++k) a = fmaf(t_params[b * 8 + k], tW1[k * 32 + d], a);
        sht[d] = __sinf(a);
    }
    __syncthreads();
    if (tid < 32) {
        float a = xb2[tid];
        for (int c = 0; c < 32; ++c) a = fmaf(shx[c], xW2[c * 32 + tid], a);
        sex[tid] = a;
    } else if (tid < 64) {
        int d = tid - 32;
        float a = tb2[d];
        for (int c = 0; c < 32; ++c) a = fmaf(sht[c], tW2[c * 32 + d], a);
        set_[d] = a;
    }
    __syncthreads();
    // ---- per-(batch,block) conditioning constants ----
    if (tid < NB * DIM) {           // tid = k*32 + d
        int k = tid >> 5, d = tid & 31;
        float a = f_bh[tid] + f_bz[tid];
        for (int c = 0; c < 32; ++c) a = fmaf(set_[c], f_Wz[(k * 34 + 2 + c) * 32 + d], a);
        sCf[tid] = a;
        float g = g_bh[tid] + g_bz[tid];
        for (int c = 0; c < 32; ++c) g = fmaf(sex[c], g_Wz[(k * 64 + 32 + c) * 32 + d], g);
        sCg[tid] = g;
    }
    __syncthreads();

    const float xj = coords[(b * 256 + j) * 2 + 0];
    const float ti = coords[(b * 256 + i) * 2 + 1];

    // ---- f-scan: h = sin(h@Wh + x*wz0 + t*wz1 + Cf) ----
    float h[DIM];
    #pragma unroll
    for (int d = 0; d < DIM; ++d) h[d] = sC0[d];

    for (int kb = 0; kb < NB; ++kb) {
        const float4* __restrict__ w4 = (const float4*)&sA[kb * DIM * DIM];
        float acc[DIM];
        #pragma unroll
        for (int d = 0; d < DIM; ++d)
            acc[d] = fmaf(xj, sfz0[kb * 32 + d], fmaf(ti, sfz1[kb * 32 + d], sCf[kb * 32 + d]));
        #pragma unroll
        for (int c = 0; c < DIM; ++c) {
            const float hc = h[c];
            #pragma unroll
            for (int q = 0; q < 8; ++q) {
                const float4 wv = w4[c * 8 + q];
                acc[4 * q + 0] = fmaf(hc, wv.x, acc[4 * q + 0]);
                acc[4 * q + 1] = fmaf(hc, wv.y, acc[4 * q + 1]);
                acc[4 * q + 2] = fmaf(hc, wv.z, acc[4 * q + 2]);
                acc[4 * q + 3] = fmaf(hc, wv.w, acc[4 * q + 3]);
            }
        }
        #pragma unroll
        for (int d = 0; d < DIM; ++d) h[d] = __sinf(acc[d]);
    }

    // ---- swap f_Wh -> g_Wh in sA ----
    __syncthreads();
    {
        const float4* src = (const float4*)g_Wh;
        float4* dst = (float4*)sA;
        for (int idx = tid; idx < NB * DIM * DIM / 4; idx += 256) dst[idx] = src[idx];
    }
    __syncthreads();

    // ---- g-scan: gh = sin(gh@Wgh + h@Wgz[:32] + Cg) ----
    float gh[DIM];
    #pragma unroll
    for (int d = 0; d < DIM; ++d) gh[d] = sG0[d];

    for (int kb = 0; kb < NB; ++kb) {
        const float4* __restrict__ wg4 = (const float4*)&sA[kb * DIM * DIM];
        const float4* __restrict__ wz4 = (const float4*)&sB[kb * DIM * DIM];
        float acc[DIM];
        #pragma unroll
        for (int d = 0; d < DIM; ++d) acc[d] = sCg[kb * 32 + d];
        #pragma unroll
        for (int c = 0; c < DIM; ++c) {
            const float hc = h[c];
            const float gc = gh[c];
            #pragma unroll
            for (int q = 0; q < 8; ++q) {
                const float4 wzv = wz4[c * 8 + q];
                const float4 wgv = wg4[c * 8 + q];
                acc[4 * q + 0] = fmaf(hc, wzv.x, fmaf(gc, wgv.x, acc[4 * q + 0]));
                acc[4 * q + 1] = fmaf(hc, wzv.y, fmaf(gc, wgv.y, acc[4 * q + 1]));
                acc[4 * q + 2] = fmaf(hc, wzv.z, fmaf(gc, wgv.z, acc[4 * q + 2]));
                acc[4 * q + 3] = fmaf(hc, wzv.w, fmaf(gc, wgv.w, acc[4 * q + 3]));
            }
        }
        #pragma unroll
        for (int d = 0; d < DIM; ++d) gh[d] = __sinf(acc[d]);
    }

    // ---- decode: u = gh @ d_W + d_b ----
    float u = d_b[0];
    #pragma unroll
    for (int d = 0; d < DIM; ++d) u = fmaf(gh[d], sdW[d], u);
    out[blockIdx.x * 256 + tid] = u;
}

extern "C" void kernel_launch(void* const* d_in, const int* in_sizes, int n_in,
                              void* d_out, int out_size, void* d_ws, size_t ws_size,
                              hipStream_t stream) {
    const float* coords   = (const float*)d_in[0];
    const float* x_params = (const float*)d_in[1];
    const float* t_params = (const float*)d_in[2];
    const float* xW1 = (const float*)d_in[3];
    const float* xb1 = (const float*)d_in[4];
    const float* xW2 = (const float*)d_in[5];
    const float* xb2 = (const float*)d_in[6];
    const float* tW1 = (const float*)d_in[7];
    const float* tb1 = (const float*)d_in[8];
    const float* tW2 = (const float*)d_in[9];
    const float* tb2 = (const float*)d_in[10];
    const float* h0  = (const float*)d_in[11];
    const float* gh0 = (const float*)d_in[12];
    const float* f_Wh = (const float*)d_in[13];
    const float* f_bh = (const float*)d_in[14];
    const float* f_Wz = (const float*)d_in[15];
    const float* f_bz = (const float*)d_in[16];
    const float* g_Wh = (const float*)d_in[17];
    const float* g_bh = (const float*)d_in[18];
    const float* g_Wz = (const float*)d_in[19];
    const float* g_bz = (const float*)d_in[20];
    const float* d_W  = (const float*)d_in[21];
    const float* d_b  = (const float*)d_in[22];

    // 16 batches * 256 i-rows = 4096 blocks; 256 j per block
    sep_kernel<<<4096, 256, 0, stream>>>(
        coords, x_params, t_params, xW1, xb1, xW2, xb2, tW1, tb1, tW2, tb2,
        h0, gh0, f_Wh, f_bh, f_Wz, f_bz, g_Wh, g_bh, g_Wz, g_bz, d_W, d_b,
        (float*)d_out);
}

// Round 3
// 285.669 us; speedup vs baseline: 2.5202x; 2.5202x over previous
//
#include <hip/hip_runtime.h>

#define DIM 32
#define NB  6

typedef __attribute__((ext_vector_type(8)))  short short8;
typedef __attribute__((ext_vector_type(16))) float floatx16;

__device__ __forceinline__ unsigned short f2bf(float f) {
    unsigned u = __float_as_uint(f);
    return (unsigned short)((u + 0x7FFF + ((u >> 16) & 1)) >> 16);
}
__device__ __forceinline__ float bf2f(unsigned short b) {
    return __uint_as_float(((unsigned)b) << 16);
}
// B-frag slot (s,h,j) holds raw channel P; C/D reg (r,h) holds raw channel Q.
__device__ __forceinline__ int Pmap(int s, int h, int j) { return 16*s + 8*(j>>2) + 4*h + (j&3); }
__device__ __forceinline__ int Qmap(int p)               { int r = p & 15, h = p >> 4; return 8*(r>>2) + 4*h + (r&3); }

#define MFMA(a, b, c) __builtin_amdgcn_mfma_f32_32x32x16_bf16((a), (b), (c), 0, 0, 0)

// LDS budget (bytes): floats 1504*4 = 6016; bf16 (36864 + 128)*2 = 73984; total 80000.
#define LDS_BYTES 80000

__global__ __launch_bounds__(256) void sep_mfma(
    const float* __restrict__ coords,
    const float* __restrict__ x_params,
    const float* __restrict__ t_params,
    const float* __restrict__ xW1, const float* __restrict__ xb1,
    const float* __restrict__ xW2, const float* __restrict__ xb2,
    const float* __restrict__ tW1, const float* __restrict__ tb1,
    const float* __restrict__ tW2, const float* __restrict__ tb2,
    const float* __restrict__ h0,  const float* __restrict__ gh0,
    const float* __restrict__ f_Wh, const float* __restrict__ f_bh,
    const float* __restrict__ f_Wz, const float* __restrict__ f_bz,
    const float* __restrict__ g_Wh, const float* __restrict__ g_bh,
    const float* __restrict__ g_Wz, const float* __restrict__ g_bz,
    const float* __restrict__ d_W,  const float* __restrict__ d_b,
    float* __restrict__ out)
{
    extern __shared__ char smem[];
    float* sCfi  = (float*)smem;          // [4][6][32] per-wave Cf + ti*fz1 (permuted)
    float* sfz0p = sCfi + 768;            // [6][32] fz0 (permuted)
    float* sCgp  = sfz0p + 192;           // [6][32] Cg (permuted)
    float* sdWp  = sCgp + 192;            // [32] d_W (permuted)
    float* shx   = sdWp + 32;
    float* sht   = shx + 32;
    float* sex   = sht + 32;
    float* set_  = sex + 32;
    float* rawCf = set_ + 32;             // [6][32] raw
    unsigned short* sImg = (unsigned short*)(rawCf + 192); // 3 mats * 6 layers * 2 s * 2 part * 512
    unsigned short* h0P  = sImg + 36864;  // [part][s][h][8]
    unsigned short* gh0P = h0P + 64;

    const int tid = threadIdx.x;
    const int b   = blockIdx.x >> 6;
    const int ig  = blockIdx.x & 63;

    // ================= PROLOGUE =================
    // P1: encoder stage 1 + A-frag image build (independent regions)
    if (tid < 32) {
        float a = xb1[tid];
        for (int k = 0; k < 16; ++k) a = fmaf(x_params[b * 16 + k], xW1[k * 32 + tid], a);
        shx[tid] = __sinf(a);
    } else if (tid < 64) {
        int d = tid - 32;
        float a = tb1[d];
        for (int k = 0; k < 8; ++k) a = fmaf(t_params[b * 8 + k], tW1[k * 32 + d], a);
        sht[d] = __sinf(a);
    }
    for (int idx = tid; idx < 9216; idx += 256) {
        int mat = idx / 3072, rem = idx % 3072;
        int l = rem >> 9, rem2 = rem & 511;
        int s = rem2 >> 8, lane = (rem2 >> 2) & 63, ip = rem2 & 3;
        int m = lane & 31, h = lane >> 5;
        int j0 = ip * 2;
        int c0 = Pmap(s, h, j0), c1 = Pmap(s, h, j0 + 1);
        float w0, w1;
        if (mat == 0)      { w0 = f_Wh[(l*32 + c0)*32 + m]; w1 = f_Wh[(l*32 + c1)*32 + m]; }
        else if (mat == 1) { w0 = g_Wh[(l*32 + c0)*32 + m]; w1 = g_Wh[(l*32 + c1)*32 + m]; }
        else               { w0 = g_Wz[(l*64 + c0)*32 + m]; w1 = g_Wz[(l*64 + c1)*32 + m]; }
        unsigned short hb0 = f2bf(w0), hb1 = f2bf(w1);
        unsigned short lb0 = f2bf(w0 - bf2f(hb0)), lb1 = f2bf(w1 - bf2f(hb1));
        int basehi = mat * 12288 + ((l * 2 + s) * 2 + 0) * 512 + lane * 8 + j0;
        sImg[basehi]       = hb0; sImg[basehi + 1]       = hb1;
        sImg[basehi + 512] = lb0; sImg[basehi + 512 + 1] = lb1;
    }
    __syncthreads();

    // P2: encoder stage 2 + fz0p + dWp + h0/gh0 packed frags
    if (tid < 32) {
        float a = xb2[tid];
        for (int c = 0; c < 32; ++c) a = fmaf(shx[c], xW2[c * 32 + tid], a);
        sex[tid] = a;
    } else if (tid < 64) {
        int d = tid - 32;
        float a = tb2[d];
        for (int c = 0; c < 32; ++c) a = fmaf(sht[c], tW2[c * 32 + d], a);
        set_[d] = a;
    }
    if (tid < 192) {
        int l = tid >> 5, p = tid & 31, d = Qmap(p);
        sfz0p[tid] = f_Wz[(l * 34 + 0) * 32 + d];
    }
    if (tid < 32) sdWp[tid] = d_W[Qmap(tid)];
    if (tid < 64) {
        int t = tid & 31;
        int s = (t >> 4) & 1, h = (t >> 3) & 1, j = t & 7;
        int c = Pmap(s, h, j);
        const float* src = (tid < 32) ? h0 : gh0;
        unsigned short* dst = (tid < 32) ? h0P : gh0P;
        float x = src[c];
        unsigned short hb = f2bf(x);
        dst[((0 * 2 + s) * 2 + h) * 8 + j] = hb;
        dst[((1 * 2 + s) * 2 + h) * 8 + j] = f2bf(x - bf2f(hb));
    }
    __syncthreads();

    // P3: raw Cf (natural order) and Cg (permuted store)
    if (tid < 192) {
        int l = tid >> 5, d = tid & 31;
        float a = f_bh[tid] + f_bz[tid];
        for (int c = 0; c < 32; ++c) a = fmaf(set_[c], f_Wz[(l * 34 + 2 + c) * 32 + d], a);
        rawCf[tid] = a;
        int p = d, dq = Qmap(p);
        float g = g_bh[l * 32 + dq] + g_bz[l * 32 + dq];
        for (int c = 0; c < 32; ++c) g = fmaf(sex[c], g_Wz[(l * 64 + 32 + c) * 32 + dq], g);
        sCgp[tid] = g;
    }
    __syncthreads();

    // P4: per-wave Cfi = Cf + ti*fz1 (permuted store)
    for (int idx = tid; idx < 768; idx += 256) {
        int w = idx / 192, r2 = idx % 192;
        int l = r2 >> 5, p = r2 & 31, d = Qmap(p);
        float ti = coords[(b * 256 + ig * 4 + w) * 2 + 1];
        sCfi[idx] = rawCf[l * 32 + d] + ti * f_Wz[(l * 34 + 1) * 32 + d];
    }
    __syncthreads();

    // ================= MAIN =================
    const int lane = tid & 63, wave = tid >> 6;
    const int i = ig * 4 + wave;
    const int e = lane & 31, hk = lane >> 5;
    const int pb = hk * 16;

    const short8 h0B1h = *(const short8*)&h0P[((0*2+0)*2 + hk) * 8];
    const short8 h0B2h = *(const short8*)&h0P[((0*2+1)*2 + hk) * 8];
    const short8 h0B1l = *(const short8*)&h0P[((1*2+0)*2 + hk) * 8];
    const short8 h0B2l = *(const short8*)&h0P[((1*2+1)*2 + hk) * 8];
    const short8 g0B1h = *(const short8*)&gh0P[((0*2+0)*2 + hk) * 8];
    const short8 g0B2h = *(const short8*)&gh0P[((0*2+1)*2 + hk) * 8];
    const short8 g0B1l = *(const short8*)&gh0P[((1*2+0)*2 + hk) * 8];
    const short8 g0B2l = *(const short8*)&gh0P[((1*2+1)*2 + hk) * 8];

    const float db = d_b[0];

    for (int tile = 0; tile < 8; ++tile) {
        const int j = tile * 32 + e;
        const float xj = coords[(b * 256 + j) * 2];

        short8 hB1h = h0B1h, hB2h = h0B2h, hB1l = h0B1l, hB2l = h0B2l;
        floatx16 acc;

        // ---- f-scan ----
        for (int l = 0; l < NB; ++l) {
            const float* cf = &sCfi[wave * 192 + l * 32 + pb];
            const float* fz = &sfz0p[l * 32 + pb];
            #pragma unroll
            for (int r = 0; r < 16; ++r) acc[r] = fmaf(xj, fz[r], cf[r]);
            const unsigned short* base = &sImg[0 * 12288 + (l * 4) * 512 + lane * 8];
            short8 ah0 = *(const short8*)(base);
            short8 al0 = *(const short8*)(base + 512);
            short8 ah1 = *(const short8*)(base + 1024);
            short8 al1 = *(const short8*)(base + 1536);
            acc = MFMA(ah0, hB1h, acc);
            acc = MFMA(ah0, hB1l, acc);
            acc = MFMA(al0, hB1h, acc);
            acc = MFMA(ah1, hB2h, acc);
            acc = MFMA(ah1, hB2l, acc);
            acc = MFMA(al1, hB2h, acc);
            #pragma unroll
            for (int r = 0; r < 8; ++r) {
                float sv = __sinf(acc[r]);
                unsigned short hb = f2bf(sv);
                hB1h[r] = (short)hb;
                hB1l[r] = (short)f2bf(sv - bf2f(hb));
            }
            #pragma unroll
            for (int r = 8; r < 16; ++r) {
                float sv = __sinf(acc[r]);
                unsigned short hb = f2bf(sv);
                hB2h[r - 8] = (short)hb;
                hB2l[r - 8] = (short)f2bf(sv - bf2f(hb));
            }
        }

        // ---- g-scan ----
        short8 gB1h = g0B1h, gB2h = g0B2h, gB1l = g0B1l, gB2l = g0B2l;
        for (int l = 0; l < NB; ++l) {
            const float* cg = &sCgp[l * 32 + pb];
            #pragma unroll
            for (int r = 0; r < 16; ++r) acc[r] = cg[r];
            const unsigned short* bh = &sImg[1 * 12288 + (l * 4) * 512 + lane * 8];
            const unsigned short* bz = &sImg[2 * 12288 + (l * 4) * 512 + lane * 8];
            short8 wh_h0 = *(const short8*)(bh);
            short8 wh_l0 = *(const short8*)(bh + 512);
            short8 wh_h1 = *(const short8*)(bh + 1024);
            short8 wh_l1 = *(const short8*)(bh + 1536);
            short8 wz_h0 = *(const short8*)(bz);
            short8 wz_l0 = *(const short8*)(bz + 512);
            short8 wz_h1 = *(const short8*)(bz + 1024);
            short8 wz_l1 = *(const short8*)(bz + 1536);
            acc = MFMA(wh_h0, gB1h, acc);
            acc = MFMA(wh_h0, gB1l, acc);
            acc = MFMA(wh_l0, gB1h, acc);
            acc = MFMA(wz_h0, hB1h, acc);
            acc = MFMA(wz_h0, hB1l, acc);
            acc = MFMA(wz_l0, hB1h, acc);
            acc = MFMA(wh_h1, gB2h, acc);
            acc = MFMA(wh_h1, gB2l, acc);
            acc = MFMA(wh_l1, gB2h, acc);
            acc = MFMA(wz_h1, hB2h, acc);
            acc = MFMA(wz_h1, hB2l, acc);
            acc = MFMA(wz_l1, hB2h, acc);
            if (l < NB - 1) {
                #pragma unroll
                for (int r = 0; r < 8; ++r) {
                    float sv = __sinf(acc[r]);
                    unsigned short hb = f2bf(sv);
                    gB1h[r] = (short)hb;
                    gB1l[r] = (short)f2bf(sv - bf2f(hb));
                }
                #pragma unroll
                for (int r = 8; r < 16; ++r) {
                    float sv = __sinf(acc[r]);
                    unsigned short hb = f2bf(sv);
                    gB2h[r - 8] = (short)hb;
                    gB2l[r - 8] = (short)f2bf(sv - bf2f(hb));
                }
            }
        }

        // ---- decode ----
        float u = 0.0f;
        #pragma unroll
        for (int r = 0; r < 16; ++r) u = fmaf(__sinf(acc[r]), sdWp[pb + r], u);
        u += __shfl_xor(u, 32);
        if (hk == 0) out[(b * 256 + i) * 256 + j] = u + db;
    }
}

extern "C" void kernel_launch(void* const* d_in, const int* in_sizes, int n_in,
                              void* d_out, int out_size, void* d_ws, size_t ws_size,
                              hipStream_t stream) {
    const float* coords   = (const float*)d_in[0];
    const float* x_params = (const float*)d_in[1];
    const float* t_params = (const float*)d_in[2];
    const float* xW1 = (const float*)d_in[3];
    const float* xb1 = (const float*)d_in[4];
    const float* xW2 = (const float*)d_in[5];
    const float* xb2 = (const float*)d_in[6];
    const float* tW1 = (const float*)d_in[7];
    const float* tb1 = (const float*)d_in[8];
    const float* tW2 = (const float*)d_in[9];
    const float* tb2 = (const float*)d_in[10];
    const float* h0  = (const float*)d_in[11];
    const float* gh0 = (const float*)d_in[12];
    const float* f_Wh = (const float*)d_in[13];
    const float* f_bh = (const float*)d_in[14];
    const float* f_Wz = (const float*)d_in[15];
    const float* f_bz = (const float*)d_in[16];
    const float* g_Wh = (const float*)d_in[17];
    const float* g_bh = (const float*)d_in[18];
    const float* g_Wz = (const float*)d_in[19];
    const float* g_bz = (const float*)d_in[20];
    const float* d_W  = (const float*)d_in[21];
    const float* d_b  = (const float*)d_in[22];

    static bool attr_set_done = false;
    hipFuncSetAttribute((const void*)sep_mfma,
                        hipFuncAttributeMaxDynamicSharedMemorySize, LDS_BYTES);
    (void)attr_set_done;

    sep_mfma<<<1024, 256, LDS_BYTES, stream>>>(
        coords, x_params, t_params, xW1, xb1, xW2, xb2, tW1, tb1, tW2, tb2,
        h0, gh0, f_Wh, f_bh, f_Wz, f_bz, g_Wh, g_bh, g_Wz, g_bz, d_W, d_b,
        (float*)d_out);
}